// Round 1
// baseline (106.089 us; speedup 1.0000x reference)
//
#include <hip/hip_runtime.h>
#include <math.h>

// YOLOv3 detection-head decode.
// prediction: [B=32, 255, 52, 52] f32 ; anchors: [3,2] f32
// out: [B, 52*52*3, 85] f32
// Per (b, gj): 255x52 tile -> transposed 52x255 with per-attr transforms.

#define BB 32
#define AA 3
#define ATTRS 85          // 5 + 80
#define NROWS 255         // AA * ATTRS
#define GG 52
#define PLANE (GG * GG)   // 2704
#define LDS_STRIDE 53     // odd pad -> bank-conflict-free transposed reads
#define STRIDE_F 8.0f     // inp_dim / G = 416/52

__global__ __launch_bounds__(256)
void detect_decode_kernel(const float* __restrict__ in,
                          const float* __restrict__ anchors,
                          float* __restrict__ out) {
    __shared__ float tile[NROWS * LDS_STRIDE];   // 54,060 B

    const int blk = blockIdx.x;        // b*GG + gj
    const int b  = blk / GG;
    const int gj = blk - b * GG;
    const int t  = threadIdx.x;

    const float* __restrict__ src = in + (size_t)b * NROWS * PLANE + (size_t)gj * GG;

    // ---- load phase: 255 rows x 13 float4 (row starts 16B-aligned) ----
    #pragma unroll 4
    for (int idx = t; idx < NROWS * 13; idx += 256) {
        const int row = idx / 13;
        const int q   = idx - row * 13;
        const float4 v = *reinterpret_cast<const float4*>(src + (size_t)row * PLANE + q * 4);
        const int l = row * LDS_STRIDE + q * 4;
        tile[l + 0] = v.x;
        tile[l + 1] = v.y;
        tile[l + 2] = v.z;
        tile[l + 3] = v.w;
    }

    __syncthreads();

    // anchors are tiny; scalar loads, broadcast via cache
    const float a0x = anchors[0], a0y = anchors[1];
    const float a1x = anchors[2], a1y = anchors[3];
    const float a2x = anchors[4], a2y = anchors[5];

    float* __restrict__ dst = out + (size_t)blk * (GG * NROWS);

    // ---- write phase: 52 x 255, coalesced contiguous stores ----
    #pragma unroll 4
    for (int idx = t; idx < GG * NROWS; idx += 256) {
        const int gi = idx / NROWS;
        const int c  = idx - gi * NROWS;          // c = a*85 + attr
        const int a    = (c >= 170) ? 2 : (c >= 85 ? 1 : 0);
        const int attr = c - a * 85;

        const float x = tile[c * LDS_STRIDE + gi];
        float r;
        if (attr >= 4) {
            // conf + class scores: sigmoid
            r = 1.0f / (1.0f + __expf(-x));
        } else if (attr == 0) {
            r = (1.0f / (1.0f + __expf(-x)) + (float)gi) * STRIDE_F;
        } else if (attr == 1) {
            r = (1.0f / (1.0f + __expf(-x)) + (float)gj) * STRIDE_F;
        } else {
            // attr 2/3: exp(t) * (anchor/stride) * stride = exp(t) * anchor
            float anc;
            if (attr == 2) anc = (a == 0) ? a0x : (a == 1) ? a1x : a2x;
            else           anc = (a == 0) ? a0y : (a == 1) ? a1y : a2y;
            r = __expf(x) * anc;
        }
        dst[idx] = r;
    }
}

extern "C" void kernel_launch(void* const* d_in, const int* in_sizes, int n_in,
                              void* d_out, int out_size, void* d_ws, size_t ws_size,
                              hipStream_t stream) {
    const float* pred    = (const float*)d_in[0];
    const float* anchors = (const float*)d_in[1];
    float* out = (float*)d_out;

    const int nblocks = BB * GG;   // one block per (b, gj) slice = 1664
    detect_decode_kernel<<<nblocks, 256, 0, stream>>>(pred, anchors, out);
}

// Round 2
// 53.632 us; speedup vs baseline: 1.9781x; 1.9781x over previous
//
#include <hip/hip_runtime.h>
#include <math.h>

// YOLOv3 detection-head decode.
// prediction: [B=32, 255, 52, 52] f32 ; anchors: [3,2] f32
// out: [B, 52*52*3, 85] f32  (flat: (b*2704+s)*255 + (a*85+attr), s=gj*52+gi)
//
// Block = (b, gj, gi-half). Half A: gi in [0,28) (7 float4/row),
// half B: gi in [28,52) (6 float4/row). LDS tile [255][29] floats = 29,580 B
// -> 5 blocks/CU residency (was 3 at 54 KB). Write phase: thread t owns
// attr-column c=t (attr decoded once), loops over gi; stride-29 LDS reads are
// bank-conflict-free (29 coprime 32), stores fully coalesced.

#define BB 32
#define GG 52
#define NROWS 255
#define PLANE (GG * GG)      // 2704
#define PAD 29
#define L2E 1.442695040889f  // log2(e)

__device__ __forceinline__ float fast_sigmoid(float x) {
    return __builtin_amdgcn_rcpf(1.0f + __builtin_amdgcn_exp2f(-L2E * x));
}

template<int GI0, int NCOL, int NQ>
__device__ __forceinline__ void decode_body(int blk,
                                            const float* __restrict__ in,
                                            const float* __restrict__ anchors,
                                            float* __restrict__ out,
                                            float* __restrict__ tile) {
    const int b  = blk / GG;
    const int gj = blk - b * GG;
    const int t  = threadIdx.x;

    const float* __restrict__ src =
        in + (size_t)b * NROWS * PLANE + gj * GG + GI0;

    // ---- load: NROWS rows x NQ float4 each (row starts 16B-aligned) ----
    constexpr int TOT = NROWS * NQ;
    #pragma unroll 4
    for (int idx = t; idx < TOT; idx += 256) {
        const int row = idx / NQ;          // constant divisor -> magic mul
        const int q   = idx - row * NQ;
        const float4 v =
            *reinterpret_cast<const float4*>(src + (size_t)row * PLANE + q * 4);
        const int l = row * PAD + q * 4;
        tile[l + 0] = v.x;
        tile[l + 1] = v.y;
        tile[l + 2] = v.z;
        tile[l + 3] = v.w;
    }

    __syncthreads();

    // ---- write: thread t owns attr-column c = t (t < 255) ----
    if (t < NROWS) {
        const int c    = t;
        const int a    = (c >= 170) ? 2 : (c >= 85 ? 1 : 0);
        const int attr = c - a * 85;

        float anc = 0.0f;
        if (attr == 2) anc = anchors[a * 2];
        else if (attr == 3) anc = anchors[a * 2 + 1];

        float* __restrict__ dst =
            out + ((size_t)(b * PLANE + gj * GG + GI0)) * NROWS + c;

        #pragma unroll 4
        for (int g = 0; g < NCOL; ++g) {
            const float x = tile[c * PAD + g];
            const float s = fast_sigmoid(x);
            float r = s;
            if (attr == 0)      r = (s + (float)(GI0 + g)) * 8.0f;
            else if (attr == 1) r = (s + (float)gj) * 8.0f;
            else if (attr == 2 || attr == 3)
                r = __builtin_amdgcn_exp2f(L2E * x) * anc;
            dst[(size_t)g * NROWS] = r;
        }
    }
}

__global__ __launch_bounds__(256)
void detect_decode_kernel(const float* __restrict__ in,
                          const float* __restrict__ anchors,
                          float* __restrict__ out) {
    __shared__ float tile[NROWS * PAD];    // 29,580 B
    const int blk = blockIdx.x;
    if (blk < BB * GG)
        decode_body<0, 28, 7>(blk, in, anchors, out, tile);
    else
        decode_body<28, 24, 6>(blk - BB * GG, in, anchors, out, tile);
}

extern "C" void kernel_launch(void* const* d_in, const int* in_sizes, int n_in,
                              void* d_out, int out_size, void* d_ws, size_t ws_size,
                              hipStream_t stream) {
    const float* pred    = (const float*)d_in[0];
    const float* anchors = (const float*)d_in[1];
    float* out = (float*)d_out;

    const int nblocks = 2 * BB * GG;   // 3328: two gi-halves per (b, gj)
    detect_decode_kernel<<<nblocks, 256, 0, stream>>>(pred, anchors, out);
}

// Round 3
// 48.529 us; speedup vs baseline: 2.1861x; 1.1051x over previous
//
#include <hip/hip_runtime.h>
#include <math.h>

// YOLOv3 detection-head decode.
// prediction: [B=32, 255, 52, 52] f32 ; anchors: [3,2] f32
// out: [B, 52*52*3, 85] f32  (flat: (b*2704 + gj*52 + gi)*255 + c, c=a*85+attr)
//
// Block = (b, gj, quarter): quarter q owns attr-rows [q*64, q*64+R), R=64
// (63 for q=3), all 52 gi. LDS tile [64][53] = 13,568 B -> 8 blocks/CU
// (32 waves, 100% occupancy). Load: R rows x 13 aligned float4 (full rows).
// Write: lane (t&63) owns column c = r0+(t&63) (attr decoded once), wave
// (t>>6) strides g by 4; stride-53 LDS reads are 2-way (free); stores are
// 256B-contiguous per wave.

#define BB 32
#define GG 52
#define NROWS 255
#define PLANE (GG * GG)      // 2704
#define PAD 53
#define L2E 1.442695040889f  // log2(e)

__device__ __forceinline__ float fast_sigmoid(float x) {
    return __builtin_amdgcn_rcpf(1.0f + __builtin_amdgcn_exp2f(-L2E * x));
}

__global__ __launch_bounds__(256)
void detect_decode_kernel(const float* __restrict__ in,
                          const float* __restrict__ anchors,
                          float* __restrict__ out) {
    __shared__ float tile[64 * PAD];   // 13,568 B

    const int blk     = blockIdx.x;
    const int quarter = blk & 3;
    const int slice   = blk >> 2;       // b*GG + gj
    const int b  = slice / GG;
    const int gj = slice - b * GG;
    const int t  = threadIdx.x;

    const int r0 = quarter * 64;
    const int R  = (quarter == 3) ? 63 : 64;

    // ---- load: R full rows x 13 float4 (row starts 16B-aligned) ----
    const float* __restrict__ src =
        in + ((size_t)(b * NROWS + r0) * GG + gj) * GG;

    for (int idx = t; idx < R * 13; idx += 256) {
        const int row = idx / 13;          // magic mul
        const int q   = idx - row * 13;
        const float4 v =
            *reinterpret_cast<const float4*>(src + (size_t)row * PLANE + q * 4);
        const int l = row * PAD + q * 4;
        tile[l + 0] = v.x;
        tile[l + 1] = v.y;
        tile[l + 2] = v.z;
        tile[l + 3] = v.w;
    }

    __syncthreads();

    // ---- write: lane owns one attr-column, wave strides over gi ----
    const int cl = t & 63;              // local column
    const int c  = r0 + cl;             // global attr index, a*85+attr
    const int w  = t >> 6;              // wave id -> starting gi

    if (c < NROWS) {
        const int a    = (c >= 170) ? 2 : (c >= 85 ? 1 : 0);
        const int attr = c - a * 85;

        float anc = 0.0f;
        if (attr == 2) anc = anchors[a * 2];
        else if (attr == 3) anc = anchors[a * 2 + 1];

        float* __restrict__ dst =
            out + ((size_t)(b * PLANE + gj * GG)) * NROWS + c;

        #pragma unroll
        for (int g = w; g < GG; g += 4) {
            const float x = tile[cl * PAD + g];
            const float s = fast_sigmoid(x);
            float r = s;
            if (attr == 0)      r = (s + (float)g) * 8.0f;
            else if (attr == 1) r = (s + (float)gj) * 8.0f;
            else if (attr == 2 || attr == 3)
                r = __builtin_amdgcn_exp2f(L2E * x) * anc;
            dst[(size_t)g * NROWS] = r;
        }
    }
}

extern "C" void kernel_launch(void* const* d_in, const int* in_sizes, int n_in,
                              void* d_out, int out_size, void* d_ws, size_t ws_size,
                              hipStream_t stream) {
    const float* pred    = (const float*)d_in[0];
    const float* anchors = (const float*)d_in[1];
    float* out = (float*)d_out;

    const int nblocks = BB * GG * 4;   // 6656: four row-quarters per (b, gj)
    detect_decode_kernel<<<nblocks, 256, 0, stream>>>(pred, anchors, out);
}